// Round 4
// baseline (3376.205 us; speedup 1.0000x reference)
//
#include <hip/hip_runtime.h>

// ---------------------------------------------------------------------------
// FlowMatchingShield: 50-step Euler sampler over a 5-layer MLP.
//   base  = state@W0[0:254]+b0            (once, MFMA K=256 padded)
//   tvec[s] = temb(s)@W0[256:320]         (once)
//   per step: h0 = silu(base+tvec+x.W0x)  (fused into tail)
//             3x 1024^3 GEMM+SiLU          (bf16 MFMA, reg-pipelined, LDS-free)
//             head W4 fused into GEMM3 (atomicAdd) + tiny tail
// Round-4: single-wave 32x32 tiles (grid 1024, 4 waves/CU), NO LDS, NO
// barriers; 8-deep register pipeline built from NAMED variables via token
// pasting (round-2's indexed arrays spilled to scratch: VGPR=48). Round-3's
// 64x64 barrier version ran 1 block/CU -> per-kt vmcnt(0) drain fully exposed.
// ---------------------------------------------------------------------------

typedef __bf16 bf16x8 __attribute__((ext_vector_type(8)));
typedef float  f32x4  __attribute__((ext_vector_type(4)));
typedef unsigned short u16;
typedef u16 u16x4 __attribute__((ext_vector_type(4)));

#define H 1024
#define BATCH 1024
#define SDIM 254
#define NSTEP 50
#define DT 0.02f

__device__ __forceinline__ u16 f2bf(float f) {
  unsigned int u = __float_as_uint(f);
  return (u16)((u + 0x7FFFu + ((u >> 16) & 1u)) >> 16);
}

__device__ __forceinline__ float silu(float v) {
  return v / (1.0f + __expf(-v));
}

// --- one-time: W[k][n] fp32 -> WT[n][k] bf16, for W1..W3 (blockIdx.z picks) --
__global__ void transpose_w(const float* __restrict__ A, const float* __restrict__ B,
                            const float* __restrict__ C, u16* __restrict__ TA,
                            u16* __restrict__ TB, u16* __restrict__ TC) {
  const float* W = (blockIdx.z == 0) ? A : (blockIdx.z == 1) ? B : C;
  u16* T = (blockIdx.z == 0) ? TA : (blockIdx.z == 1) ? TB : TC;
  __shared__ float tile[32][33];
  const int n0 = blockIdx.x * 32, k0 = blockIdx.y * 32;
  const int tx = threadIdx.x & 31, ty = threadIdx.x >> 5;  // 32 x 8
#pragma unroll
  for (int i = 0; i < 4; ++i)
    tile[ty + 8 * i][tx] = W[(k0 + ty + 8 * i) * H + n0 + tx];
  __syncthreads();
#pragma unroll
  for (int i = 0; i < 4; ++i)
    T[(size_t)(n0 + ty + 8 * i) * H + k0 + tx] = f2bf(tile[tx][ty + 8 * i]);
}

// --- one-time: W0[k][n] (k<256) -> w0t[n][k] bf16 [1024][256] ----------------
__global__ void transpose_w0(const float* __restrict__ W0, u16* __restrict__ T) {
  __shared__ float tile[32][33];
  const int n0 = blockIdx.x * 32, k0 = blockIdx.y * 32;
  const int tx = threadIdx.x & 31, ty = threadIdx.x >> 5;
#pragma unroll
  for (int i = 0; i < 4; ++i)
    tile[ty + 8 * i][tx] = W0[(k0 + ty + 8 * i) * H + n0 + tx];
  __syncthreads();
#pragma unroll
  for (int i = 0; i < 4; ++i)
    T[(size_t)(n0 + ty + 8 * i) * 256 + k0 + tx] = f2bf(tile[tx][ty + 8 * i]);
}

// --- one-time: state fp32 [1024][254] -> bf16 [1024][256] zero-padded --------
__global__ void prep_state(const float* __restrict__ state, u16* __restrict__ sb) {
  const int row = blockIdx.x, col = threadIdx.x;  // 256 threads
  sb[row * 256 + col] = (col < SDIM) ? f2bf(state[row * SDIM + col]) : (u16)0;
}

// --- one-time: tvec[s][h] = sum_j sin(t fj) W0[256+j][h] + cos(t fj) W0[288+j][h]
__global__ void tvec_kernel(const float* __restrict__ W0, float* __restrict__ tvec) {
  const int s = blockIdx.x;
  const int h = blockIdx.y * 256 + threadIdx.x;
  const float t = (float)s * DT;
  float acc = 0.0f;
#pragma unroll
  for (int j = 0; j < 32; ++j) {
    float fr = __expf((float)j * (-9.210340371976184f / 31.0f));
    float ang = t * fr;
    acc += __sinf(ang) * W0[(256 + j) * H + h] + __cosf(ang) * W0[(288 + j) * H + h];
  }
  tvec[s * H + h] = acc;
}

// --- one-time: h0 for step 0 (bf16) + seed x into d_out + zero v -------------
__global__ void init_kernel(const float* __restrict__ base, const float* __restrict__ tvec,
                            const float* __restrict__ x0, const float* __restrict__ W0,
                            u16* __restrict__ h0, float* __restrict__ xout,
                            float* __restrict__ v) {
  const int b = blockIdx.x, tid = threadIdx.x;
  const float xa = x0[2 * b], xb = x0[2 * b + 1];
  if (tid == 0) { xout[2 * b] = xa; xout[2 * b + 1] = xb; }
  if (tid < 2) v[2 * b + tid] = 0.0f;
  const int n = tid * 4;
  float4 bs = *(const float4*)&base[(size_t)b * H + n];
  float4 tv = *(const float4*)&tvec[n];
  float4 wa = *(const float4*)&W0[254 * H + n];
  float4 wb = *(const float4*)&W0[255 * H + n];
  u16x4 r;
  r[0] = f2bf(silu(bs.x + tv.x + xa * wa.x + xb * wb.x));
  r[1] = f2bf(silu(bs.y + tv.y + xa * wa.y + xb * wb.y));
  r[2] = f2bf(silu(bs.z + tv.z + xa * wa.z + xb * wb.z));
  r[3] = f2bf(silu(bs.w + tv.w + xa * wa.w + xb * wb.w));
  *(u16x4*)&h0[(size_t)b * H + n] = r;
}

// --- main GEMM: single-wave 32x32 tile, LDS-free, 8-deep register pipeline.
// A bf16 [1024][K] row-major, BT bf16 [1024][K] row-major (pre-transposed).
// MODE 0: silu->bf16 store. MODE 2: +bias fp32 store (base). MODE 3: silu,
// fuse head: atomicAdd(v[row][0:2], silu(h3) @ W4), no store.
#define DECL_BLK(s) bf16x8 a0##s, a1##s, b0##s, b1##s;
#define LOAD_BLK(s, idx)      \
  a0##s = Ap0[(idx) * 4];     \
  a1##s = Ap1[(idx) * 4];     \
  b0##s = Bp0[(idx) * 4];     \
  b1##s = Bp1[(idx) * 4];
#define MFMA_BLK(s)                                                          \
  c00 = __builtin_amdgcn_mfma_f32_16x16x32_bf16(a0##s, b0##s, c00, 0, 0, 0); \
  c01 = __builtin_amdgcn_mfma_f32_16x16x32_bf16(a0##s, b1##s, c01, 0, 0, 0); \
  c10 = __builtin_amdgcn_mfma_f32_16x16x32_bf16(a1##s, b0##s, c10, 0, 0, 0); \
  c11 = __builtin_amdgcn_mfma_f32_16x16x32_bf16(a1##s, b1##s, c11, 0, 0, 0);

template <int KTILES, int MODE>
__global__ __launch_bounds__(64) void gemm32r(const u16* __restrict__ A,
                                              const u16* __restrict__ BT,
                                              const float* __restrict__ bias,
                                              void* __restrict__ out,
                                              const float* __restrict__ W4,
                                              float* __restrict__ v) {
  constexpr int K = KTILES * 32;
  const int lane = threadIdx.x;
  const int lr = lane & 15, quad = lane >> 4;
  // XCD swizzle: lin&7 = XCD; each XCD covers 4 bm-stripes x all bn, so its
  // B working set (2 MiB) + A stripes (256 KiB) stay in its 4 MiB L2.
  const int lin = blockIdx.x;
  const int bm = (lin & 7) | (((lin >> 8) & 3) << 3);
  const int bn = (lin >> 3) & 31;

  const bf16x8* Ap0 = (const bf16x8*)(A + (size_t)(bm * 32 + lr) * K + quad * 8);
  const bf16x8* Ap1 = (const bf16x8*)(A + (size_t)(bm * 32 + 16 + lr) * K + quad * 8);
  const bf16x8* Bp0 = (const bf16x8*)(BT + (size_t)(bn * 32 + lr) * K + quad * 8);
  const bf16x8* Bp1 = (const bf16x8*)(BT + (size_t)(bn * 32 + 16 + lr) * K + quad * 8);

  f32x4 c00 = {}, c01 = {}, c10 = {}, c11 = {};
  DECL_BLK(0) DECL_BLK(1) DECL_BLK(2) DECL_BLK(3)
  DECL_BLK(4) DECL_BLK(5) DECL_BLK(6) DECL_BLK(7)

  // prologue: fill all 8 stages (32 outstanding dwordx4 loads)
  LOAD_BLK(0, 0) LOAD_BLK(1, 1) LOAD_BLK(2, 2) LOAD_BLK(3, 3)
  LOAD_BLK(4, 4) LOAD_BLK(5, 5) LOAD_BLK(6, 6) LOAD_BLK(7, 7)

  int kt = 0;
  for (; kt + 8 < KTILES; kt += 8) {
    MFMA_BLK(0) LOAD_BLK(0, kt + 8)
    MFMA_BLK(1) LOAD_BLK(1, kt + 9)
    MFMA_BLK(2) LOAD_BLK(2, kt + 10)
    MFMA_BLK(3) LOAD_BLK(3, kt + 11)
    MFMA_BLK(4) LOAD_BLK(4, kt + 12)
    MFMA_BLK(5) LOAD_BLK(5, kt + 13)
    MFMA_BLK(6) LOAD_BLK(6, kt + 14)
    MFMA_BLK(7) LOAD_BLK(7, kt + 15)
  }
  MFMA_BLK(0) MFMA_BLK(1) MFMA_BLK(2) MFMA_BLK(3)
  MFMA_BLK(4) MFMA_BLK(5) MFMA_BLK(6) MFMA_BLK(7)

  const int gn0 = bn * 32 + lr;
  const int gn1 = gn0 + 16;
  const float bb0 = bias[gn0], bb1 = bias[gn1];
  const int gm = bm * 32 + quad * 4;

  if (MODE == 3) {
    const float w4a0 = W4[2 * gn0], w4b0 = W4[2 * gn0 + 1];
    const float w4a1 = W4[2 * gn1], w4b1 = W4[2 * gn1 + 1];
#pragma unroll
    for (int r = 0; r < 4; ++r) {
      // rows gm+r (c00/c01) and gm+16+r (c10/c11)
      float sa0 = silu(c00[r] + bb0), sb0 = silu(c01[r] + bb1);
      float sa1 = silu(c10[r] + bb0), sb1 = silu(c11[r] + bb1);
      float p0 = sa0 * w4a0 + sb0 * w4a1;
      float p1 = sa0 * w4b0 + sb0 * w4b1;
      float q0 = sa1 * w4a0 + sb1 * w4a1;
      float q1 = sa1 * w4b0 + sb1 * w4b1;
      p0 += __shfl_xor(p0, 1); p0 += __shfl_xor(p0, 2);
      p0 += __shfl_xor(p0, 4); p0 += __shfl_xor(p0, 8);
      p1 += __shfl_xor(p1, 1); p1 += __shfl_xor(p1, 2);
      p1 += __shfl_xor(p1, 4); p1 += __shfl_xor(p1, 8);
      q0 += __shfl_xor(q0, 1); q0 += __shfl_xor(q0, 2);
      q0 += __shfl_xor(q0, 4); q0 += __shfl_xor(q0, 8);
      q1 += __shfl_xor(q1, 1); q1 += __shfl_xor(q1, 2);
      q1 += __shfl_xor(q1, 4); q1 += __shfl_xor(q1, 8);
      if (lr == 0) {
        atomicAdd(&v[2 * (gm + r)], p0);
        atomicAdd(&v[2 * (gm + r) + 1], p1);
        atomicAdd(&v[2 * (gm + 16 + r)], q0);
        atomicAdd(&v[2 * (gm + 16 + r) + 1], q1);
      }
    }
  } else {
#pragma unroll
    for (int r = 0; r < 4; ++r) {
      float x00 = c00[r] + bb0, x01 = c01[r] + bb1;
      float x10 = c10[r] + bb0, x11 = c11[r] + bb1;
      if (MODE == 0) {
        ((u16*)out)[(size_t)(gm + r) * H + gn0] = f2bf(silu(x00));
        ((u16*)out)[(size_t)(gm + r) * H + gn1] = f2bf(silu(x01));
        ((u16*)out)[(size_t)(gm + 16 + r) * H + gn0] = f2bf(silu(x10));
        ((u16*)out)[(size_t)(gm + 16 + r) * H + gn1] = f2bf(silu(x11));
      } else {
        ((float*)out)[(size_t)(gm + r) * H + gn0] = x00;
        ((float*)out)[(size_t)(gm + r) * H + gn1] = x01;
        ((float*)out)[(size_t)(gm + 16 + r) * H + gn0] = x10;
        ((float*)out)[(size_t)(gm + 16 + r) * H + gn1] = x11;
      }
    }
  }
}

// --- per-step tail: x += dt*(v+b4) ; zero v ; h0(next) = silu(base+tvec+x.W0x)
__global__ void tail2_kernel(float* __restrict__ v, const float* __restrict__ b4,
                             float* __restrict__ x, const float* __restrict__ base,
                             const float* __restrict__ tvec, const float* __restrict__ W0,
                             u16* __restrict__ h0, int s) {
  const int b = blockIdx.x, tid = threadIdx.x;
  const float va = v[2 * b], vb = v[2 * b + 1];
  __syncthreads();
  const float xa = x[2 * b] + DT * (va + b4[0]);
  const float xb = x[2 * b + 1] + DT * (vb + b4[1]);
  if (tid == 0) {
    x[2 * b] = xa; x[2 * b + 1] = xb;
    v[2 * b] = 0.0f; v[2 * b + 1] = 0.0f;  // ready for next step's atomics
  }
  if (s < NSTEP - 1) {
    const int n = tid * 4;
    float4 bs = *(const float4*)&base[(size_t)b * H + n];
    float4 tv = *(const float4*)&tvec[(size_t)(s + 1) * H + n];
    float4 wa = *(const float4*)&W0[254 * H + n];
    float4 wb = *(const float4*)&W0[255 * H + n];
    u16x4 r;
    r[0] = f2bf(silu(bs.x + tv.x + xa * wa.x + xb * wb.x));
    r[1] = f2bf(silu(bs.y + tv.y + xa * wa.y + xb * wb.y));
    r[2] = f2bf(silu(bs.z + tv.z + xa * wa.z + xb * wb.z));
    r[3] = f2bf(silu(bs.w + tv.w + xa * wa.w + xb * wb.w));
    *(u16x4*)&h0[(size_t)b * H + n] = r;
  }
}

extern "C" void kernel_launch(void* const* d_in, const int* in_sizes, int n_in,
                              void* d_out, int out_size, void* d_ws, size_t ws_size,
                              hipStream_t stream) {
  const float* state = (const float*)d_in[0];
  const float* x0    = (const float*)d_in[1];
  const float* W0    = (const float*)d_in[2];
  const float* b0    = (const float*)d_in[3];
  const float* W1    = (const float*)d_in[4];
  const float* b1    = (const float*)d_in[5];
  const float* W2    = (const float*)d_in[6];
  const float* b2    = (const float*)d_in[7];
  const float* W3    = (const float*)d_in[8];
  const float* b3    = (const float*)d_in[9];
  const float* W4    = (const float*)d_in[10];
  const float* b4    = (const float*)d_in[11];
  float* xout = (float*)d_out;

  char* ws = (char*)d_ws;
  const size_t MB = 1024 * 1024;
  float* base = (float*)(ws + 0);                 // 4 MiB
  float* tvec = (float*)(ws + 4 * MB);            // 200 KiB (reserve 256 KiB)
  float* v    = (float*)(ws + 4 * MB + 256 * 1024);  // 8 KiB (reserve 768 KiB)
  u16* w1t = (u16*)(ws + 5 * MB);                 // 2 MiB each
  u16* w2t = (u16*)(ws + 7 * MB);
  u16* w3t = (u16*)(ws + 9 * MB);
  u16* hA  = (u16*)(ws + 11 * MB);                // 2 MiB each
  u16* hB  = (u16*)(ws + 13 * MB);
  u16* hC  = (u16*)(ws + 15 * MB);
  u16* w0t = (u16*)(ws + 17 * MB);                // 512 KiB [1024][256]
  u16* stb = (u16*)(ws + 17 * MB + 512 * 1024);   // 512 KiB [1024][256]

  transpose_w<<<dim3(32, 32, 3), 256, 0, stream>>>(W1, W2, W3, w1t, w2t, w3t);
  transpose_w0<<<dim3(32, 8), 256, 0, stream>>>(W0, w0t);
  prep_state<<<BATCH, 256, 0, stream>>>(state, stb);
  gemm32r<8, 2><<<1024, 64, 0, stream>>>(stb, w0t, b0, base, nullptr, nullptr);
  tvec_kernel<<<dim3(NSTEP, 4), 256, 0, stream>>>(W0, tvec);
  init_kernel<<<BATCH, 256, 0, stream>>>(base, tvec, x0, W0, hA, xout, v);

  for (int s = 0; s < NSTEP; ++s) {
    gemm32r<32, 0><<<1024, 64, 0, stream>>>(hA, w1t, b1, hB, nullptr, nullptr);
    gemm32r<32, 0><<<1024, 64, 0, stream>>>(hB, w2t, b2, hC, nullptr, nullptr);
    gemm32r<32, 3><<<1024, 64, 0, stream>>>(hC, w3t, b3, nullptr, W4, v);
    tail2_kernel<<<BATCH, 256, 0, stream>>>(v, b4, xout, base, tvec, W0, hA, s);
  }
}

// Round 5
// 3323.762 us; speedup vs baseline: 1.0158x; 1.0158x over previous
//
#include <hip/hip_runtime.h>

// ---------------------------------------------------------------------------
// FlowMatchingShield: 50-step Euler sampler over a 5-layer MLP.
//   base  = state@W0[0:254]+b0            (once, MFMA K=256 padded)
//   tvec[s] = temb(s)@W0[256:320]         (once)
//   per step: h0 = silu(base+tvec+x.W0x)  (fused into tail)
//             3x 1024^3 GEMM+SiLU          (bf16 MFMA, depth-4 reg pipeline)
//             head W4 fused into GEMM3 (atomicAdd) + tiny tail
// Round-5: single-wave 32x32 tiles (grid 1024, 1 wave/SIMD), NO LDS/barriers,
// depth-4 NAMED-register pipeline + __launch_bounds__(64,1).
//   r2: indexed arrays -> scratch spill (VGPR=48).  r3: 1 block/CU barrier
//   drain (13.5us).  r4: depth-8 (32 instr/wave) oversaturated vmem queues ->
//   L_eff ~12000cy (20us/GEMM). Depth-4 = BW-delay product (~16KB/CU in
//   flight vs ~23KB needed) without queue collapse.
// ---------------------------------------------------------------------------

typedef __bf16 bf16x8 __attribute__((ext_vector_type(8)));
typedef float  f32x4  __attribute__((ext_vector_type(4)));
typedef unsigned short u16;
typedef u16 u16x4 __attribute__((ext_vector_type(4)));

#define H 1024
#define BATCH 1024
#define SDIM 254
#define NSTEP 50
#define DT 0.02f

__device__ __forceinline__ u16 f2bf(float f) {
  unsigned int u = __float_as_uint(f);
  return (u16)((u + 0x7FFFu + ((u >> 16) & 1u)) >> 16);
}

__device__ __forceinline__ float silu(float v) {
  return v / (1.0f + __expf(-v));
}

// --- one-time: W[k][n] fp32 -> WT[n][k] bf16, for W1..W3 (blockIdx.z picks) --
__global__ void transpose_w(const float* __restrict__ A, const float* __restrict__ B,
                            const float* __restrict__ C, u16* __restrict__ TA,
                            u16* __restrict__ TB, u16* __restrict__ TC) {
  const float* W = (blockIdx.z == 0) ? A : (blockIdx.z == 1) ? B : C;
  u16* T = (blockIdx.z == 0) ? TA : (blockIdx.z == 1) ? TB : TC;
  __shared__ float tile[32][33];
  const int n0 = blockIdx.x * 32, k0 = blockIdx.y * 32;
  const int tx = threadIdx.x & 31, ty = threadIdx.x >> 5;  // 32 x 8
#pragma unroll
  for (int i = 0; i < 4; ++i)
    tile[ty + 8 * i][tx] = W[(k0 + ty + 8 * i) * H + n0 + tx];
  __syncthreads();
#pragma unroll
  for (int i = 0; i < 4; ++i)
    T[(size_t)(n0 + ty + 8 * i) * H + k0 + tx] = f2bf(tile[tx][ty + 8 * i]);
}

// --- one-time: W0[k][n] (k<256) -> w0t[n][k] bf16 [1024][256] ----------------
__global__ void transpose_w0(const float* __restrict__ W0, u16* __restrict__ T) {
  __shared__ float tile[32][33];
  const int n0 = blockIdx.x * 32, k0 = blockIdx.y * 32;
  const int tx = threadIdx.x & 31, ty = threadIdx.x >> 5;
#pragma unroll
  for (int i = 0; i < 4; ++i)
    tile[ty + 8 * i][tx] = W0[(k0 + ty + 8 * i) * H + n0 + tx];
  __syncthreads();
#pragma unroll
  for (int i = 0; i < 4; ++i)
    T[(size_t)(n0 + ty + 8 * i) * 256 + k0 + tx] = f2bf(tile[tx][ty + 8 * i]);
}

// --- one-time: state fp32 [1024][254] -> bf16 [1024][256] zero-padded --------
__global__ void prep_state(const float* __restrict__ state, u16* __restrict__ sb) {
  const int row = blockIdx.x, col = threadIdx.x;  // 256 threads
  sb[row * 256 + col] = (col < SDIM) ? f2bf(state[row * SDIM + col]) : (u16)0;
}

// --- one-time: tvec[s][h] = sum_j sin(t fj) W0[256+j][h] + cos(t fj) W0[288+j][h]
__global__ void tvec_kernel(const float* __restrict__ W0, float* __restrict__ tvec) {
  const int s = blockIdx.x;
  const int h = blockIdx.y * 256 + threadIdx.x;
  const float t = (float)s * DT;
  float acc = 0.0f;
#pragma unroll
  for (int j = 0; j < 32; ++j) {
    float fr = __expf((float)j * (-9.210340371976184f / 31.0f));
    float ang = t * fr;
    acc += __sinf(ang) * W0[(256 + j) * H + h] + __cosf(ang) * W0[(288 + j) * H + h];
  }
  tvec[s * H + h] = acc;
}

// --- one-time: h0 for step 0 (bf16) + seed x into d_out + zero v -------------
__global__ void init_kernel(const float* __restrict__ base, const float* __restrict__ tvec,
                            const float* __restrict__ x0, const float* __restrict__ W0,
                            u16* __restrict__ h0, float* __restrict__ xout,
                            float* __restrict__ v) {
  const int b = blockIdx.x, tid = threadIdx.x;
  const float xa = x0[2 * b], xb = x0[2 * b + 1];
  if (tid == 0) { xout[2 * b] = xa; xout[2 * b + 1] = xb; }
  if (tid < 2) v[2 * b + tid] = 0.0f;
  const int n = tid * 4;
  float4 bs = *(const float4*)&base[(size_t)b * H + n];
  float4 tv = *(const float4*)&tvec[n];
  float4 wa = *(const float4*)&W0[254 * H + n];
  float4 wb = *(const float4*)&W0[255 * H + n];
  u16x4 r;
  r[0] = f2bf(silu(bs.x + tv.x + xa * wa.x + xb * wb.x));
  r[1] = f2bf(silu(bs.y + tv.y + xa * wa.y + xb * wb.y));
  r[2] = f2bf(silu(bs.z + tv.z + xa * wa.z + xb * wb.z));
  r[3] = f2bf(silu(bs.w + tv.w + xa * wa.w + xb * wb.w));
  *(u16x4*)&h0[(size_t)b * H + n] = r;
}

// --- main GEMM: single-wave 32x32 tile, LDS-free, depth-4 register pipeline.
// A bf16 [1024][K] row-major, BT bf16 [1024][K] row-major (pre-transposed).
// MODE 0: silu->bf16 store. MODE 2: +bias fp32 store (base). MODE 3: silu,
// fuse head: atomicAdd(v[row][0:2], silu(h3) @ W4), no store.
#define DECL_BLK(s) bf16x8 a0##s, a1##s, b0##s, b1##s;
#define LOAD_BLK(s, idx)      \
  a0##s = Ap0[(idx) * 4];     \
  a1##s = Ap1[(idx) * 4];     \
  b0##s = Bp0[(idx) * 4];     \
  b1##s = Bp1[(idx) * 4];
#define MFMA_BLK(s)                                                          \
  c00 = __builtin_amdgcn_mfma_f32_16x16x32_bf16(a0##s, b0##s, c00, 0, 0, 0); \
  c01 = __builtin_amdgcn_mfma_f32_16x16x32_bf16(a0##s, b1##s, c01, 0, 0, 0); \
  c10 = __builtin_amdgcn_mfma_f32_16x16x32_bf16(a1##s, b0##s, c10, 0, 0, 0); \
  c11 = __builtin_amdgcn_mfma_f32_16x16x32_bf16(a1##s, b1##s, c11, 0, 0, 0);

template <int KTILES, int MODE>
__global__ __launch_bounds__(64, 1) void gemm32r(const u16* __restrict__ A,
                                                 const u16* __restrict__ BT,
                                                 const float* __restrict__ bias,
                                                 void* __restrict__ out,
                                                 const float* __restrict__ W4,
                                                 float* __restrict__ v) {
  constexpr int K = KTILES * 32;
  const int lane = threadIdx.x;
  const int lr = lane & 15, quad = lane >> 4;
  // XCD swizzle: lin&7 = XCD; per XCD: 4 bm-stripes x all bn -> A 256 KiB +
  // B 2 MiB working set inside the 4 MiB per-XCD L2.
  const int lin = blockIdx.x;
  const int bm = (lin & 7) | (((lin >> 8) & 3) << 3);
  const int bn = (lin >> 3) & 31;

  const bf16x8* Ap0 = (const bf16x8*)(A + (size_t)(bm * 32 + lr) * K + quad * 8);
  const bf16x8* Ap1 = (const bf16x8*)(A + (size_t)(bm * 32 + 16 + lr) * K + quad * 8);
  const bf16x8* Bp0 = (const bf16x8*)(BT + (size_t)(bn * 32 + lr) * K + quad * 8);
  const bf16x8* Bp1 = (const bf16x8*)(BT + (size_t)(bn * 32 + 16 + lr) * K + quad * 8);

  f32x4 c00 = {}, c01 = {}, c10 = {}, c11 = {};
  DECL_BLK(0) DECL_BLK(1) DECL_BLK(2) DECL_BLK(3)

  // prologue: fill 4 stages (16 outstanding dwordx4 loads/wave, 64/CU)
  LOAD_BLK(0, 0) LOAD_BLK(1, 1) LOAD_BLK(2, 2) LOAD_BLK(3, 3)

  int kt = 0;
  for (; kt + 4 < KTILES; kt += 4) {
    MFMA_BLK(0) LOAD_BLK(0, kt + 4)
    MFMA_BLK(1) LOAD_BLK(1, kt + 5)
    MFMA_BLK(2) LOAD_BLK(2, kt + 6)
    MFMA_BLK(3) LOAD_BLK(3, kt + 7)
  }
  MFMA_BLK(0) MFMA_BLK(1) MFMA_BLK(2) MFMA_BLK(3)

  const int gn0 = bn * 32 + lr;
  const int gn1 = gn0 + 16;
  const float bb0 = bias[gn0], bb1 = bias[gn1];
  const int gm = bm * 32 + quad * 4;

  if (MODE == 3) {
    const float w4a0 = W4[2 * gn0], w4b0 = W4[2 * gn0 + 1];
    const float w4a1 = W4[2 * gn1], w4b1 = W4[2 * gn1 + 1];
#pragma unroll
    for (int r = 0; r < 4; ++r) {
      // rows gm+r (c00/c01) and gm+16+r (c10/c11)
      float sa0 = silu(c00[r] + bb0), sb0 = silu(c01[r] + bb1);
      float sa1 = silu(c10[r] + bb0), sb1 = silu(c11[r] + bb1);
      float p0 = sa0 * w4a0 + sb0 * w4a1;
      float p1 = sa0 * w4b0 + sb0 * w4b1;
      float q0 = sa1 * w4a0 + sb1 * w4a1;
      float q1 = sa1 * w4b0 + sb1 * w4b1;
      p0 += __shfl_xor(p0, 1); p0 += __shfl_xor(p0, 2);
      p0 += __shfl_xor(p0, 4); p0 += __shfl_xor(p0, 8);
      p1 += __shfl_xor(p1, 1); p1 += __shfl_xor(p1, 2);
      p1 += __shfl_xor(p1, 4); p1 += __shfl_xor(p1, 8);
      q0 += __shfl_xor(q0, 1); q0 += __shfl_xor(q0, 2);
      q0 += __shfl_xor(q0, 4); q0 += __shfl_xor(q0, 8);
      q1 += __shfl_xor(q1, 1); q1 += __shfl_xor(q1, 2);
      q1 += __shfl_xor(q1, 4); q1 += __shfl_xor(q1, 8);
      if (lr == 0) {
        atomicAdd(&v[2 * (gm + r)], p0);
        atomicAdd(&v[2 * (gm + r) + 1], p1);
        atomicAdd(&v[2 * (gm + 16 + r)], q0);
        atomicAdd(&v[2 * (gm + 16 + r) + 1], q1);
      }
    }
  } else {
#pragma unroll
    for (int r = 0; r < 4; ++r) {
      float x00 = c00[r] + bb0, x01 = c01[r] + bb1;
      float x10 = c10[r] + bb0, x11 = c11[r] + bb1;
      if (MODE == 0) {
        ((u16*)out)[(size_t)(gm + r) * H + gn0] = f2bf(silu(x00));
        ((u16*)out)[(size_t)(gm + r) * H + gn1] = f2bf(silu(x01));
        ((u16*)out)[(size_t)(gm + 16 + r) * H + gn0] = f2bf(silu(x10));
        ((u16*)out)[(size_t)(gm + 16 + r) * H + gn1] = f2bf(silu(x11));
      } else {
        ((float*)out)[(size_t)(gm + r) * H + gn0] = x00;
        ((float*)out)[(size_t)(gm + r) * H + gn1] = x01;
        ((float*)out)[(size_t)(gm + 16 + r) * H + gn0] = x10;
        ((float*)out)[(size_t)(gm + 16 + r) * H + gn1] = x11;
      }
    }
  }
}

// --- per-step tail: x += dt*(v+b4) ; zero v ; h0(next) = silu(base+tvec+x.W0x)
__global__ void tail2_kernel(float* __restrict__ v, const float* __restrict__ b4,
                             float* __restrict__ x, const float* __restrict__ base,
                             const float* __restrict__ tvec, const float* __restrict__ W0,
                             u16* __restrict__ h0, int s) {
  const int b = blockIdx.x, tid = threadIdx.x;
  const float va = v[2 * b], vb = v[2 * b + 1];
  __syncthreads();
  const float xa = x[2 * b] + DT * (va + b4[0]);
  const float xb = x[2 * b + 1] + DT * (vb + b4[1]);
  if (tid == 0) {
    x[2 * b] = xa; x[2 * b + 1] = xb;
    v[2 * b] = 0.0f; v[2 * b + 1] = 0.0f;  // ready for next step's atomics
  }
  if (s < NSTEP - 1) {
    const int n = tid * 4;
    float4 bs = *(const float4*)&base[(size_t)b * H + n];
    float4 tv = *(const float4*)&tvec[(size_t)(s + 1) * H + n];
    float4 wa = *(const float4*)&W0[254 * H + n];
    float4 wb = *(const float4*)&W0[255 * H + n];
    u16x4 r;
    r[0] = f2bf(silu(bs.x + tv.x + xa * wa.x + xb * wb.x));
    r[1] = f2bf(silu(bs.y + tv.y + xa * wa.y + xb * wb.y));
    r[2] = f2bf(silu(bs.z + tv.z + xa * wa.z + xb * wb.z));
    r[3] = f2bf(silu(bs.w + tv.w + xa * wa.w + xb * wb.w));
    *(u16x4*)&h0[(size_t)b * H + n] = r;
  }
}

extern "C" void kernel_launch(void* const* d_in, const int* in_sizes, int n_in,
                              void* d_out, int out_size, void* d_ws, size_t ws_size,
                              hipStream_t stream) {
  const float* state = (const float*)d_in[0];
  const float* x0    = (const float*)d_in[1];
  const float* W0    = (const float*)d_in[2];
  const float* b0    = (const float*)d_in[3];
  const float* W1    = (const float*)d_in[4];
  const float* b1    = (const float*)d_in[5];
  const float* W2    = (const float*)d_in[6];
  const float* b2    = (const float*)d_in[7];
  const float* W3    = (const float*)d_in[8];
  const float* b3    = (const float*)d_in[9];
  const float* W4    = (const float*)d_in[10];
  const float* b4    = (const float*)d_in[11];
  float* xout = (float*)d_out;

  char* ws = (char*)d_ws;
  const size_t MB = 1024 * 1024;
  float* base = (float*)(ws + 0);                 // 4 MiB
  float* tvec = (float*)(ws + 4 * MB);            // 200 KiB (reserve 256 KiB)
  float* v    = (float*)(ws + 4 * MB + 256 * 1024);  // 8 KiB (reserve 768 KiB)
  u16* w1t = (u16*)(ws + 5 * MB);                 // 2 MiB each
  u16* w2t = (u16*)(ws + 7 * MB);
  u16* w3t = (u16*)(ws + 9 * MB);
  u16* hA  = (u16*)(ws + 11 * MB);                // 2 MiB each
  u16* hB  = (u16*)(ws + 13 * MB);
  u16* hC  = (u16*)(ws + 15 * MB);
  u16* w0t = (u16*)(ws + 17 * MB);                // 512 KiB [1024][256]
  u16* stb = (u16*)(ws + 17 * MB + 512 * 1024);   // 512 KiB [1024][256]

  transpose_w<<<dim3(32, 32, 3), 256, 0, stream>>>(W1, W2, W3, w1t, w2t, w3t);
  transpose_w0<<<dim3(32, 8), 256, 0, stream>>>(W0, w0t);
  prep_state<<<BATCH, 256, 0, stream>>>(state, stb);
  gemm32r<8, 2><<<1024, 64, 0, stream>>>(stb, w0t, b0, base, nullptr, nullptr);
  tvec_kernel<<<dim3(NSTEP, 4), 256, 0, stream>>>(W0, tvec);
  init_kernel<<<BATCH, 256, 0, stream>>>(base, tvec, x0, W0, hA, xout, v);

  for (int s = 0; s < NSTEP; ++s) {
    gemm32r<32, 0><<<1024, 64, 0, stream>>>(hA, w1t, b1, hB, nullptr, nullptr);
    gemm32r<32, 0><<<1024, 64, 0, stream>>>(hB, w2t, b2, hC, nullptr, nullptr);
    gemm32r<32, 3><<<1024, 64, 0, stream>>>(hC, w3t, b3, nullptr, W4, v);
    tail2_kernel<<<BATCH, 256, 0, stream>>>(v, b4, xout, base, tvec, W0, hA, s);
  }
}

// Round 6
// 2036.142 us; speedup vs baseline: 1.6581x; 1.6324x over previous
//
#include <hip/hip_runtime.h>

// ---------------------------------------------------------------------------
// FlowMatchingShield: 50-step Euler sampler over a 5-layer MLP.
//   base  = state@W0[0:254]+b0            (once, MFMA K=256 padded)
//   tvec[s] = temb(s)@W0[256:320]         (once)
//   per step: h0 = silu(base+tvec+x.W0x)  (fused into tail)
//             3x 1024^3 GEMM+SiLU          (bf16 MFMA, LDS-staged, depth-2)
//             head W4 fused into GEMM3 (atomicAdd) + tiny tail
// Round-6: back to round-1's WAITCNT-FRIENDLY structure
// (global->reg->LDS->reg->MFMA, single-wave 32x32 tile, no barriers,
// 4 blocks/CU) with DEPTH-2 register prefetch. Ladder so far:
//   r1 LDS depth-1: 10.7us/GEMM.  r2 indexed arrays: scratch spill.
//   r3 64x64 1 block/CU: barrier vmcnt(0) drain 13.5us.
//   r4/r5 direct global->MFMA depth-8/4: ~20us — compiler emits
//   conservative (vmcnt(0)-class) waits when MFMA reads load-result VGPRs
//   directly; ds_write consumers get fine-grained vmcnt (m97 asm evidence).
// Depth-2 covers ~2 chain-lengths (~600cy) of L2 latency vs r1's ~300.
// ---------------------------------------------------------------------------

typedef __bf16 bf16x8 __attribute__((ext_vector_type(8)));
typedef float  f32x4  __attribute__((ext_vector_type(4)));
typedef unsigned short u16;
typedef u16 u16x4 __attribute__((ext_vector_type(4)));

#define H 1024
#define BATCH 1024
#define SDIM 254
#define NSTEP 50
#define DT 0.02f
#define LDP 40  // padded LDS row stride (u16 elems): 80B; 2-way bank alias = free

__device__ __forceinline__ u16 f2bf(float f) {
  unsigned int u = __float_as_uint(f);
  return (u16)((u + 0x7FFFu + ((u >> 16) & 1u)) >> 16);
}

__device__ __forceinline__ float silu(float v) {
  return v / (1.0f + __expf(-v));
}

// --- one-time: W[k][n] fp32 -> WT[n][k] bf16, for W1..W3 (blockIdx.z picks) --
__global__ void transpose_w(const float* __restrict__ A, const float* __restrict__ B,
                            const float* __restrict__ C, u16* __restrict__ TA,
                            u16* __restrict__ TB, u16* __restrict__ TC) {
  const float* W = (blockIdx.z == 0) ? A : (blockIdx.z == 1) ? B : C;
  u16* T = (blockIdx.z == 0) ? TA : (blockIdx.z == 1) ? TB : TC;
  __shared__ float tile[32][33];
  const int n0 = blockIdx.x * 32, k0 = blockIdx.y * 32;
  const int tx = threadIdx.x & 31, ty = threadIdx.x >> 5;  // 32 x 8
#pragma unroll
  for (int i = 0; i < 4; ++i)
    tile[ty + 8 * i][tx] = W[(k0 + ty + 8 * i) * H + n0 + tx];
  __syncthreads();
#pragma unroll
  for (int i = 0; i < 4; ++i)
    T[(size_t)(n0 + ty + 8 * i) * H + k0 + tx] = f2bf(tile[tx][ty + 8 * i]);
}

// --- one-time: W0[k][n] (k<256) -> w0t[n][k] bf16 [1024][256] ----------------
__global__ void transpose_w0(const float* __restrict__ W0, u16* __restrict__ T) {
  __shared__ float tile[32][33];
  const int n0 = blockIdx.x * 32, k0 = blockIdx.y * 32;
  const int tx = threadIdx.x & 31, ty = threadIdx.x >> 5;
#pragma unroll
  for (int i = 0; i < 4; ++i)
    tile[ty + 8 * i][tx] = W0[(k0 + ty + 8 * i) * H + n0 + tx];
  __syncthreads();
#pragma unroll
  for (int i = 0; i < 4; ++i)
    T[(size_t)(n0 + ty + 8 * i) * 256 + k0 + tx] = f2bf(tile[tx][ty + 8 * i]);
}

// --- one-time: state fp32 [1024][254] -> bf16 [1024][256] zero-padded --------
__global__ void prep_state(const float* __restrict__ state, u16* __restrict__ sb) {
  const int row = blockIdx.x, col = threadIdx.x;  // 256 threads
  sb[row * 256 + col] = (col < SDIM) ? f2bf(state[row * SDIM + col]) : (u16)0;
}

// --- one-time: tvec[s][h] = sum_j sin(t fj) W0[256+j][h] + cos(t fj) W0[288+j][h]
__global__ void tvec_kernel(const float* __restrict__ W0, float* __restrict__ tvec) {
  const int s = blockIdx.x;
  const int h = blockIdx.y * 256 + threadIdx.x;
  const float t = (float)s * DT;
  float acc = 0.0f;
#pragma unroll
  for (int j = 0; j < 32; ++j) {
    float fr = __expf((float)j * (-9.210340371976184f / 31.0f));
    float ang = t * fr;
    acc += __sinf(ang) * W0[(256 + j) * H + h] + __cosf(ang) * W0[(288 + j) * H + h];
  }
  tvec[s * H + h] = acc;
}

// --- one-time: h0 for step 0 (bf16) + seed x into d_out + zero v -------------
__global__ void init_kernel(const float* __restrict__ base, const float* __restrict__ tvec,
                            const float* __restrict__ x0, const float* __restrict__ W0,
                            u16* __restrict__ h0, float* __restrict__ xout,
                            float* __restrict__ v) {
  const int b = blockIdx.x, tid = threadIdx.x;
  const float xa = x0[2 * b], xb = x0[2 * b + 1];
  if (tid == 0) { xout[2 * b] = xa; xout[2 * b + 1] = xb; }
  if (tid < 2) v[2 * b + tid] = 0.0f;
  const int n = tid * 4;
  float4 bs = *(const float4*)&base[(size_t)b * H + n];
  float4 tv = *(const float4*)&tvec[n];
  float4 wa = *(const float4*)&W0[254 * H + n];
  float4 wb = *(const float4*)&W0[255 * H + n];
  u16x4 r;
  r[0] = f2bf(silu(bs.x + tv.x + xa * wa.x + xb * wb.x));
  r[1] = f2bf(silu(bs.y + tv.y + xa * wa.y + xb * wb.y));
  r[2] = f2bf(silu(bs.z + tv.z + xa * wa.z + xb * wb.z));
  r[3] = f2bf(silu(bs.w + tv.w + xa * wa.w + xb * wb.w));
  *(u16x4*)&h0[(size_t)b * H + n] = r;
}

// --- main GEMM: single-wave 32x32 tile, LDS-staged, depth-2 reg prefetch.
// A bf16 [1024][K] row-major, BT bf16 [1024][K] row-major (pre-transposed).
// MODE 0: silu->bf16 store. MODE 2: +bias fp32 store (base). MODE 3: silu,
// fuse head: atomicAdd(v[row][0:2], silu(h3) @ W4), no store.
#define DECL_STG(s) bf16x8 ra0##s, ra1##s, rb0##s, rb1##s;
#define LOADG(s, idx)            \
  ra0##s = Gp_a0[(idx) * 4];     \
  ra1##s = Gp_a1[(idx) * 4];     \
  rb0##s = Gp_b0[(idx) * 4];     \
  rb1##s = Gp_b1[(idx) * 4];
#define STORE_LDS(s)                        \
  *(bf16x8*)&As[sw0] = ra0##s;              \
  *(bf16x8*)&As[sw1] = ra1##s;              \
  *(bf16x8*)&Bs[sw0] = rb0##s;              \
  *(bf16x8*)&Bs[sw1] = rb1##s;
#define COMPUTE()                                                            \
  {                                                                          \
    bf16x8 fa0 = *(const bf16x8*)&As[f_a0];                                  \
    bf16x8 fa1 = *(const bf16x8*)&As[f_a1];                                  \
    bf16x8 fb0 = *(const bf16x8*)&Bs[f_a0];                                  \
    bf16x8 fb1 = *(const bf16x8*)&Bs[f_a1];                                  \
    c00 = __builtin_amdgcn_mfma_f32_16x16x32_bf16(fa0, fb0, c00, 0, 0, 0);   \
    c01 = __builtin_amdgcn_mfma_f32_16x16x32_bf16(fa0, fb1, c01, 0, 0, 0);   \
    c10 = __builtin_amdgcn_mfma_f32_16x16x32_bf16(fa1, fb0, c10, 0, 0, 0);   \
    c11 = __builtin_amdgcn_mfma_f32_16x16x32_bf16(fa1, fb1, c11, 0, 0, 0);   \
  }

template <int KTILES, int MODE>
__global__ __launch_bounds__(64, 1) void gemm32(const u16* __restrict__ A,
                                                const u16* __restrict__ BT,
                                                const float* __restrict__ bias,
                                                void* __restrict__ out,
                                                const float* __restrict__ W4,
                                                float* __restrict__ v) {
  constexpr int K = KTILES * 32;
  __shared__ u16 As[32 * LDP];
  __shared__ u16 Bs[32 * LDP];
  const int lane = threadIdx.x;
  const int lr = lane & 15, quad = lane >> 4;
  // XCD swizzle: lin&7 = XCD; per XCD: 4 bm-stripes x all bn -> A 256 KiB +
  // B 2 MiB working set inside the 4 MiB per-XCD L2.
  const int lin = blockIdx.x;
  const int bm = (lin & 7) | (((lin >> 8) & 3) << 3);
  const int bn = (lin >> 3) & 31;

  // staging: thread -> global row srow/srow+16, col skc (64B/row per 4 lanes)
  const int srow = lane >> 2;      // 0..15
  const int skc = (lane & 3) * 8;  // 0,8,16,24
  const bf16x8* Gp_a0 = (const bf16x8*)(A + (size_t)(bm * 32 + srow) * K + skc);
  const bf16x8* Gp_a1 = (const bf16x8*)(A + (size_t)(bm * 32 + 16 + srow) * K + skc);
  const bf16x8* Gp_b0 = (const bf16x8*)(BT + (size_t)(bn * 32 + srow) * K + skc);
  const bf16x8* Gp_b1 = (const bf16x8*)(BT + (size_t)(bn * 32 + 16 + srow) * K + skc);
  const int sw0 = srow * LDP + skc;
  const int sw1 = (srow + 16) * LDP + skc;

  // fragment offsets (u16 elems)
  const int f_a0 = lr * LDP + quad * 8;
  const int f_a1 = (16 + lr) * LDP + quad * 8;

  f32x4 c00 = {}, c01 = {}, c10 = {}, c11 = {};
  DECL_STG(0) DECL_STG(1)

  // depth-2 prologue: tiles 0 and 1 in flight
  LOADG(0, 0) LOADG(1, 1)

  int kt = 0;
  for (; kt + 2 < KTILES; kt += 2) {
    // tile kt (set 0): stage to LDS, refill set 0 with tile kt+2, compute.
    // In-wave DS-pipe ordering makes write-after-prior-read safe; compiler
    // emits precise vmcnt before the ds_writes and lgkmcnt before MFMAs.
    STORE_LDS(0) LOADG(0, kt + 2) COMPUTE()
    STORE_LDS(1) LOADG(1, kt + 3) COMPUTE()
  }
  STORE_LDS(0) COMPUTE()
  STORE_LDS(1) COMPUTE()

  const int gn0 = bn * 32 + lr;
  const int gn1 = gn0 + 16;
  const float bb0 = bias[gn0], bb1 = bias[gn1];
  const int gm = bm * 32 + quad * 4;

  if (MODE == 3) {
    const float w4a0 = W4[2 * gn0], w4b0 = W4[2 * gn0 + 1];
    const float w4a1 = W4[2 * gn1], w4b1 = W4[2 * gn1 + 1];
#pragma unroll
    for (int r = 0; r < 4; ++r) {
      // rows gm+r (c00/c01) and gm+16+r (c10/c11)
      float sa0 = silu(c00[r] + bb0), sb0 = silu(c01[r] + bb1);
      float sa1 = silu(c10[r] + bb0), sb1 = silu(c11[r] + bb1);
      float p0 = sa0 * w4a0 + sb0 * w4a1;
      float p1 = sa0 * w4b0 + sb0 * w4b1;
      float q0 = sa1 * w4a0 + sb1 * w4a1;
      float q1 = sa1 * w4b0 + sb1 * w4b1;
      p0 += __shfl_xor(p0, 1); p0 += __shfl_xor(p0, 2);
      p0 += __shfl_xor(p0, 4); p0 += __shfl_xor(p0, 8);
      p1 += __shfl_xor(p1, 1); p1 += __shfl_xor(p1, 2);
      p1 += __shfl_xor(p1, 4); p1 += __shfl_xor(p1, 8);
      q0 += __shfl_xor(q0, 1); q0 += __shfl_xor(q0, 2);
      q0 += __shfl_xor(q0, 4); q0 += __shfl_xor(q0, 8);
      q1 += __shfl_xor(q1, 1); q1 += __shfl_xor(q1, 2);
      q1 += __shfl_xor(q1, 4); q1 += __shfl_xor(q1, 8);
      if (lr == 0) {
        atomicAdd(&v[2 * (gm + r)], p0);
        atomicAdd(&v[2 * (gm + r) + 1], p1);
        atomicAdd(&v[2 * (gm + 16 + r)], q0);
        atomicAdd(&v[2 * (gm + 16 + r) + 1], q1);
      }
    }
  } else {
#pragma unroll
    for (int r = 0; r < 4; ++r) {
      float x00 = c00[r] + bb0, x01 = c01[r] + bb1;
      float x10 = c10[r] + bb0, x11 = c11[r] + bb1;
      if (MODE == 0) {
        ((u16*)out)[(size_t)(gm + r) * H + gn0] = f2bf(silu(x00));
        ((u16*)out)[(size_t)(gm + r) * H + gn1] = f2bf(silu(x01));
        ((u16*)out)[(size_t)(gm + 16 + r) * H + gn0] = f2bf(silu(x10));
        ((u16*)out)[(size_t)(gm + 16 + r) * H + gn1] = f2bf(silu(x11));
      } else {
        ((float*)out)[(size_t)(gm + r) * H + gn0] = x00;
        ((float*)out)[(size_t)(gm + r) * H + gn1] = x01;
        ((float*)out)[(size_t)(gm + 16 + r) * H + gn0] = x10;
        ((float*)out)[(size_t)(gm + 16 + r) * H + gn1] = x11;
      }
    }
  }
}

// --- per-step tail: x += dt*(v+b4) ; zero v ; h0(next) = silu(base+tvec+x.W0x)
__global__ void tail2_kernel(float* __restrict__ v, const float* __restrict__ b4,
                             float* __restrict__ x, const float* __restrict__ base,
                             const float* __restrict__ tvec, const float* __restrict__ W0,
                             u16* __restrict__ h0, int s) {
  const int b = blockIdx.x, tid = threadIdx.x;
  const float va = v[2 * b], vb = v[2 * b + 1];
  __syncthreads();
  const float xa = x[2 * b] + DT * (va + b4[0]);
  const float xb = x[2 * b + 1] + DT * (vb + b4[1]);
  if (tid == 0) {
    x[2 * b] = xa; x[2 * b + 1] = xb;
    v[2 * b] = 0.0f; v[2 * b + 1] = 0.0f;  // ready for next step's atomics
  }
  if (s < NSTEP - 1) {
    const int n = tid * 4;
    float4 bs = *(const float4*)&base[(size_t)b * H + n];
    float4 tv = *(const float4*)&tvec[(size_t)(s + 1) * H + n];
    float4 wa = *(const float4*)&W0[254 * H + n];
    float4 wb = *(const float4*)&W0[255 * H + n];
    u16x4 r;
    r[0] = f2bf(silu(bs.x + tv.x + xa * wa.x + xb * wb.x));
    r[1] = f2bf(silu(bs.y + tv.y + xa * wa.y + xb * wb.y));
    r[2] = f2bf(silu(bs.z + tv.z + xa * wa.z + xb * wb.z));
    r[3] = f2bf(silu(bs.w + tv.w + xa * wa.w + xb * wb.w));
    *(u16x4*)&h0[(size_t)b * H + n] = r;
  }
}

extern "C" void kernel_launch(void* const* d_in, const int* in_sizes, int n_in,
                              void* d_out, int out_size, void* d_ws, size_t ws_size,
                              hipStream_t stream) {
  const float* state = (const float*)d_in[0];
  const float* x0    = (const float*)d_in[1];
  const float* W0    = (const float*)d_in[2];
  const float* b0    = (const float*)d_in[3];
  const float* W1    = (const float*)d_in[4];
  const float* b1    = (const float*)d_in[5];
  const float* W2    = (const float*)d_in[6];
  const float* b2    = (const float*)d_in[7];
  const float* W3    = (const float*)d_in[8];
  const float* b3    = (const float*)d_in[9];
  const float* W4    = (const float*)d_in[10];
  const float* b4    = (const float*)d_in[11];
  float* xout = (float*)d_out;

  char* ws = (char*)d_ws;
  const size_t MB = 1024 * 1024;
  float* base = (float*)(ws + 0);                 // 4 MiB
  float* tvec = (float*)(ws + 4 * MB);            // 200 KiB (reserve 256 KiB)
  float* v    = (float*)(ws + 4 * MB + 256 * 1024);  // 8 KiB (reserve 768 KiB)
  u16* w1t = (u16*)(ws + 5 * MB);                 // 2 MiB each
  u16* w2t = (u16*)(ws + 7 * MB);
  u16* w3t = (u16*)(ws + 9 * MB);
  u16* hA  = (u16*)(ws + 11 * MB);                // 2 MiB each
  u16* hB  = (u16*)(ws + 13 * MB);
  u16* hC  = (u16*)(ws + 15 * MB);
  u16* w0t = (u16*)(ws + 17 * MB);                // 512 KiB [1024][256]
  u16* stb = (u16*)(ws + 17 * MB + 512 * 1024);   // 512 KiB [1024][256]

  transpose_w<<<dim3(32, 32, 3), 256, 0, stream>>>(W1, W2, W3, w1t, w2t, w3t);
  transpose_w0<<<dim3(32, 8), 256, 0, stream>>>(W0, w0t);
  prep_state<<<BATCH, 256, 0, stream>>>(state, stb);
  gemm32<8, 2><<<1024, 64, 0, stream>>>(stb, w0t, b0, base, nullptr, nullptr);
  tvec_kernel<<<dim3(NSTEP, 4), 256, 0, stream>>>(W0, tvec);
  init_kernel<<<BATCH, 256, 0, stream>>>(base, tvec, x0, W0, hA, xout, v);

  for (int s = 0; s < NSTEP; ++s) {
    gemm32<32, 0><<<1024, 64, 0, stream>>>(hA, w1t, b1, hB, nullptr, nullptr);
    gemm32<32, 0><<<1024, 64, 0, stream>>>(hB, w2t, b2, hC, nullptr, nullptr);
    gemm32<32, 3><<<1024, 64, 0, stream>>>(hC, w3t, b3, nullptr, W4, v);
    tail2_kernel<<<BATCH, 256, 0, stream>>>(v, b4, xout, base, tvec, W0, hA, s);
  }
}